// Round 1
// baseline (531.283 us; speedup 1.0000x reference)
//
#include <hip/hip_runtime.h>

#define B_SZ   4096
#define T_SZ   512
#define F_SZ   32
#define S_SZ   64
#define H_SZ   128
#define OUT_SZ 32
#define PH_SZ  6

#define ROWS_PER_WG 8   // 4 waves * 2 rows each
#define THREADS     256

__device__ __forceinline__ float tanh_fast(float x) {
  // tanh(x) = 1 - 2/(exp(2x)+1); exact at +/-inf, ~1e-7 abs error elsewhere
  float e = __expf(2.0f * x);
  return 1.0f - 2.0f / (e + 1.0f);
}

__global__ __launch_bounds__(THREADS) void ssm_scan_kernel(
    const float* __restrict__ x, const float* __restrict__ pl,
    const float* __restrict__ W_A, const float* __restrict__ W_B,
    const float* __restrict__ W_C, const float* __restrict__ b_C,
    const float* __restrict__ W_ctrl, const float* __restrict__ b_ctrl,
    const float* __restrict__ W1, const float* __restrict__ b1,
    const float* __restrict__ W2, const float* __restrict__ b2,
    float* __restrict__ out) {
  __shared__ __align__(16) float s_state[2][ROWS_PER_WG][S_SZ];  // 4 KB
  __shared__ __align__(16) float s_x[2][ROWS_PER_WG][F_SZ];      // 2 KB
  __shared__ __align__(16) float s_obs[ROWS_PER_WG][H_SZ];       // 4 KB
  __shared__ __align__(16) float s_h1[ROWS_PER_WG][H_SZ];        // 4 KB

  const int tid  = threadIdx.x;
  const int lane = tid & 63;
  const int wave = tid >> 6;
  const int lr0  = wave * 2;      // local row 0 of this wave
  const int lr1  = lr0 + 1;       // local row 1
  const int row_base = blockIdx.x * ROWS_PER_WG;
  const int r0 = row_base + lr0;
  const int r1 = row_base + lr1;

  // ---- load W_A row `lane` and W_B row `lane` into registers ----
  float a[S_SZ];
  float wb[F_SZ];
#pragma unroll
  for (int jc = 0; jc < S_SZ / 4; ++jc) {
    float4 v = reinterpret_cast<const float4*>(W_A + (size_t)lane * S_SZ)[jc];
    a[jc * 4 + 0] = v.x; a[jc * 4 + 1] = v.y;
    a[jc * 4 + 2] = v.z; a[jc * 4 + 3] = v.w;
  }
#pragma unroll
  for (int fc = 0; fc < F_SZ / 4; ++fc) {
    float4 v = reinterpret_cast<const float4*>(W_B + (size_t)lane * F_SZ)[fc];
    wb[fc * 4 + 0] = v.x; wb[fc * 4 + 1] = v.y;
    wb[fc * 4 + 2] = v.z; wb[fc * 4 + 3] = v.w;
  }

  // ---- control[r][lane] = b_ctrl[lane] + sum_p W_ctrl[lane][p] * pl[r][p] ----
  float ctrl0 = b_ctrl[lane];
  float ctrl1 = ctrl0;
#pragma unroll
  for (int p = 0; p < PH_SZ; ++p) {
    float wcp = W_ctrl[lane * PH_SZ + p];
    ctrl0 = fmaf(wcp, pl[(size_t)r0 * PH_SZ + p], ctrl0);
    ctrl1 = fmaf(wcp, pl[(size_t)r1 * PH_SZ + p], ctrl1);
  }

  // per-lane x staging: lanes 0-31 -> local row lr0, lanes 32-63 -> lr1
  const int xlr = lr0 + (lane >> 5);
  const int xf  = lane & 31;
  const float* xg = x + ((size_t)(row_base + xlr) * T_SZ + 0) * F_SZ + xf;

  // ---- prologue: state0 = 0, stage x[t=0] ----
  s_state[0][lr0][lane] = 0.0f;
  s_state[0][lr1][lane] = 0.0f;
  s_x[0][xlr][xf] = xg[0];
  __syncthreads();

  // ---- the scan ----
#pragma unroll 2
  for (int t = 0; t < T_SZ; ++t) {
    const int cur = t & 1;
    const int nxt = cur ^ 1;

    // register-prefetch next x slice (latency hidden under the FMAs below)
    float xnext = 0.0f;
    if (t + 1 < T_SZ) xnext = xg[(size_t)(t + 1) * F_SZ];

    float acc0 = ctrl0, acc1 = ctrl1;

    // bx = W_B @ x_t  (broadcast LDS reads)
    const float4* xr0 = reinterpret_cast<const float4*>(&s_x[cur][lr0][0]);
    const float4* xr1 = reinterpret_cast<const float4*>(&s_x[cur][lr1][0]);
#pragma unroll
    for (int fc = 0; fc < F_SZ / 4; ++fc) {
      float4 v0 = xr0[fc];
      float4 v1 = xr1[fc];
      acc0 = fmaf(wb[fc * 4 + 0], v0.x, acc0);
      acc0 = fmaf(wb[fc * 4 + 1], v0.y, acc0);
      acc0 = fmaf(wb[fc * 4 + 2], v0.z, acc0);
      acc0 = fmaf(wb[fc * 4 + 3], v0.w, acc0);
      acc1 = fmaf(wb[fc * 4 + 0], v1.x, acc1);
      acc1 = fmaf(wb[fc * 4 + 1], v1.y, acc1);
      acc1 = fmaf(wb[fc * 4 + 2], v1.z, acc1);
      acc1 = fmaf(wb[fc * 4 + 3], v1.w, acc1);
    }

    // A @ state  (broadcast LDS reads)
    const float4* sr0 = reinterpret_cast<const float4*>(&s_state[cur][lr0][0]);
    const float4* sr1 = reinterpret_cast<const float4*>(&s_state[cur][lr1][0]);
#pragma unroll
    for (int jc = 0; jc < S_SZ / 4; ++jc) {
      float4 v0 = sr0[jc];
      float4 v1 = sr1[jc];
      acc0 = fmaf(a[jc * 4 + 0], v0.x, acc0);
      acc0 = fmaf(a[jc * 4 + 1], v0.y, acc0);
      acc0 = fmaf(a[jc * 4 + 2], v0.z, acc0);
      acc0 = fmaf(a[jc * 4 + 3], v0.w, acc0);
      acc1 = fmaf(a[jc * 4 + 0], v1.x, acc1);
      acc1 = fmaf(a[jc * 4 + 1], v1.y, acc1);
      acc1 = fmaf(a[jc * 4 + 2], v1.z, acc1);
      acc1 = fmaf(a[jc * 4 + 3], v1.w, acc1);
    }

    float ns0 = tanh_fast(acc0);
    float ns1 = tanh_fast(acc1);
    s_state[nxt][lr0][lane] = ns0;
    s_state[nxt][lr1][lane] = ns1;
    if (t + 1 < T_SZ) s_x[nxt][xlr][xf] = xnext;
    __syncthreads();
  }

  // final state is in buffer 0 (T even). Tail projections.
  const int r_t = tid >> 5;   // 0..7 local row
  const int c_t = tid & 31;   // 0..31

  // observation = W_C @ state + b_C   -> s_obs[r][0..127]
  {
    const float* srow = &s_state[0][r_t][0];
#pragma unroll
    for (int k = 0; k < 4; ++k) {
      const int h = c_t + k * 32;
      float acc = b_C[h];
      const float4* wc = reinterpret_cast<const float4*>(W_C + (size_t)h * S_SZ);
      const float4* sv = reinterpret_cast<const float4*>(srow);
#pragma unroll
      for (int j = 0; j < S_SZ / 4; ++j) {
        float4 w = wc[j];
        float4 s = sv[j];
        acc = fmaf(w.x, s.x, acc);
        acc = fmaf(w.y, s.y, acc);
        acc = fmaf(w.z, s.z, acc);
        acc = fmaf(w.w, s.w, acc);
      }
      s_obs[r_t][h] = acc;
    }
  }
  __syncthreads();

  // h1 = relu(W1 @ obs + b1) -> s_h1[r][0..127]
  {
    const float4* ov = reinterpret_cast<const float4*>(&s_obs[r_t][0]);
#pragma unroll
    for (int k = 0; k < 4; ++k) {
      const int h = c_t + k * 32;
      float acc = b1[h];
      const float4* w1 = reinterpret_cast<const float4*>(W1 + (size_t)h * H_SZ);
#pragma unroll
      for (int j = 0; j < H_SZ / 4; ++j) {
        float4 w = w1[j];
        float4 o = ov[j];
        acc = fmaf(w.x, o.x, acc);
        acc = fmaf(w.y, o.y, acc);
        acc = fmaf(w.z, o.z, acc);
        acc = fmaf(w.w, o.w, acc);
      }
      s_h1[r_t][h] = fmaxf(acc, 0.0f);
    }
  }
  __syncthreads();

  // out = W2 @ h1 + b2  (one output element per thread; coalesced store)
  {
    float acc = b2[c_t];
    const float4* w2 = reinterpret_cast<const float4*>(W2 + (size_t)c_t * H_SZ);
    const float4* hv = reinterpret_cast<const float4*>(&s_h1[r_t][0]);
#pragma unroll
    for (int j = 0; j < H_SZ / 4; ++j) {
      float4 w = w2[j];
      float4 h = hv[j];
      acc = fmaf(w.x, h.x, acc);
      acc = fmaf(w.y, h.y, acc);
      acc = fmaf(w.z, h.z, acc);
      acc = fmaf(w.w, h.w, acc);
    }
    out[(size_t)(row_base + r_t) * OUT_SZ + c_t] = acc;
  }
}

extern "C" void kernel_launch(void* const* d_in, const int* in_sizes, int n_in,
                              void* d_out, int out_size, void* d_ws, size_t ws_size,
                              hipStream_t stream) {
  (void)in_sizes; (void)n_in; (void)out_size; (void)d_ws; (void)ws_size;
  const float* x      = (const float*)d_in[0];
  const float* pl     = (const float*)d_in[1];
  const float* W_A    = (const float*)d_in[2];
  const float* W_B    = (const float*)d_in[3];
  const float* W_C    = (const float*)d_in[4];
  const float* b_C    = (const float*)d_in[5];
  const float* W_ctrl = (const float*)d_in[6];
  const float* b_ctrl = (const float*)d_in[7];
  const float* W1     = (const float*)d_in[8];
  const float* b1     = (const float*)d_in[9];
  const float* W2     = (const float*)d_in[10];
  const float* b2     = (const float*)d_in[11];
  float* out = (float*)d_out;

  dim3 grid(B_SZ / ROWS_PER_WG);
  dim3 block(THREADS);
  hipLaunchKernelGGL(ssm_scan_kernel, grid, block, 0, stream,
                     x, pl, W_A, W_B, W_C, b_C, W_ctrl, b_ctrl,
                     W1, b1, W2, b2, out);
}

// Round 2
// 516.037 us; speedup vs baseline: 1.0295x; 1.0295x over previous
//
#include <hip/hip_runtime.h>

#define B_SZ   4096
#define T_SZ   512
#define F_SZ   32
#define S_SZ   64
#define H_SZ   128
#define OUT_SZ 32
#define PH_SZ  6

#define ROWS_PER_WG 8   // 4 waves * 2 rows each
#define THREADS     256

__device__ __forceinline__ float tanh_fast(float x) {
  // tanh(x) = 1 - 2/(exp(2x)+1); exact at +/-inf, ~1e-7 abs error elsewhere
  float e = __expf(2.0f * x);
  return 1.0f - 2.0f / (e + 1.0f);
}

// min 2 waves/EU -> VGPR cap 256: lets a[64]+wb[32] stay register-resident.
__global__ __launch_bounds__(THREADS, 2) void ssm_scan_kernel(
    const float* __restrict__ x, const float* __restrict__ pl,
    const float* __restrict__ W_A, const float* __restrict__ W_B,
    const float* __restrict__ W_C, const float* __restrict__ b_C,
    const float* __restrict__ W_ctrl, const float* __restrict__ b_ctrl,
    const float* __restrict__ W1, const float* __restrict__ b1,
    const float* __restrict__ W2, const float* __restrict__ b2,
    float* __restrict__ out) {
  // All LDS below is WAVE-LOCAL: wave w touches only rows 2w, 2w+1.
  // No __syncthreads anywhere; wave-internal LDS RAW ordering is lgkmcnt.
  __shared__ __align__(16) float s_state[2][ROWS_PER_WG][S_SZ];  // 4 KB
  __shared__ __align__(16) float s_x[2][ROWS_PER_WG][F_SZ];      // 2 KB
  __shared__ __align__(16) float s_obs[ROWS_PER_WG][H_SZ];       // 4 KB
  __shared__ __align__(16) float s_h1[ROWS_PER_WG][H_SZ];        // 4 KB

  const int tid  = threadIdx.x;
  const int lane = tid & 63;
  const int wave = tid >> 6;
  const int lr0  = wave * 2;
  const int lr1  = lr0 + 1;
  const int row_base = blockIdx.x * ROWS_PER_WG;
  const int r0 = row_base + lr0;
  const int r1 = row_base + lr1;

  // ---- W_A row `lane` and W_B row `lane` into registers ----
  float a[S_SZ];
  float wb[F_SZ];
#pragma unroll
  for (int jc = 0; jc < S_SZ / 4; ++jc) {
    float4 v = reinterpret_cast<const float4*>(W_A + (size_t)lane * S_SZ)[jc];
    a[jc * 4 + 0] = v.x; a[jc * 4 + 1] = v.y;
    a[jc * 4 + 2] = v.z; a[jc * 4 + 3] = v.w;
  }
#pragma unroll
  for (int fc = 0; fc < F_SZ / 4; ++fc) {
    float4 v = reinterpret_cast<const float4*>(W_B + (size_t)lane * F_SZ)[fc];
    wb[fc * 4 + 0] = v.x; wb[fc * 4 + 1] = v.y;
    wb[fc * 4 + 2] = v.z; wb[fc * 4 + 3] = v.w;
  }

  // ---- control[r][lane] ----
  float ctrl0 = b_ctrl[lane];
  float ctrl1 = ctrl0;
#pragma unroll
  for (int p = 0; p < PH_SZ; ++p) {
    float wcp = W_ctrl[lane * PH_SZ + p];
    ctrl0 = fmaf(wcp, pl[(size_t)r0 * PH_SZ + p], ctrl0);
    ctrl1 = fmaf(wcp, pl[(size_t)r1 * PH_SZ + p], ctrl1);
  }

  // per-lane x staging: lanes 0-31 -> row lr0, lanes 32-63 -> lr1
  const int xlr = lr0 + (lane >> 5);
  const int xf  = lane & 31;
  const float* xg = x + ((size_t)(row_base + xlr) * T_SZ) * F_SZ + xf;

  // ---- prologue: state0 = 0; stage x[0]; prefetch x[1] ----
  s_state[0][lr0][lane] = 0.0f;
  s_state[0][lr1][lane] = 0.0f;
  s_x[0][xlr][xf] = xg[0];
  float xn1 = xg[1 * F_SZ];   // x[t+1], written to LDS during step t

  // ---- the scan (no barriers; everything wave-local) ----
#pragma unroll 2
  for (int t = 0; t < T_SZ; ++t) {
    const int cur = t & 1;
    const int nxt = cur ^ 1;

    // prefetch x[t+2] (index clamped branchlessly; duplicate read harmless)
    float xn2 = xg[(size_t)((t + 2) & (T_SZ - 1)) * F_SZ];
    // stage x[t+1] into the buffer we are NOT reading this step
    s_x[nxt][xlr][xf] = xn1;

    // two accumulation chains per row -> 4 independent chains per wave
    float acc0a = ctrl0, acc1a = ctrl1;
    float acc0b = 0.0f,  acc1b = 0.0f;

    // bx = W_B @ x_t (broadcast LDS reads)
    const float4* xr0 = reinterpret_cast<const float4*>(&s_x[cur][lr0][0]);
    const float4* xr1 = reinterpret_cast<const float4*>(&s_x[cur][lr1][0]);
#pragma unroll
    for (int fc = 0; fc < F_SZ / 4; ++fc) {
      float4 v0 = xr0[fc];
      float4 v1 = xr1[fc];
      acc0a = fmaf(wb[fc * 4 + 0], v0.x, acc0a);
      acc0b = fmaf(wb[fc * 4 + 1], v0.y, acc0b);
      acc0a = fmaf(wb[fc * 4 + 2], v0.z, acc0a);
      acc0b = fmaf(wb[fc * 4 + 3], v0.w, acc0b);
      acc1a = fmaf(wb[fc * 4 + 0], v1.x, acc1a);
      acc1b = fmaf(wb[fc * 4 + 1], v1.y, acc1b);
      acc1a = fmaf(wb[fc * 4 + 2], v1.z, acc1a);
      acc1b = fmaf(wb[fc * 4 + 3], v1.w, acc1b);
    }

    // A @ state (broadcast LDS reads)
    const float4* sr0 = reinterpret_cast<const float4*>(&s_state[cur][lr0][0]);
    const float4* sr1 = reinterpret_cast<const float4*>(&s_state[cur][lr1][0]);
#pragma unroll
    for (int jc = 0; jc < S_SZ / 4; ++jc) {
      float4 v0 = sr0[jc];
      float4 v1 = sr1[jc];
      acc0a = fmaf(a[jc * 4 + 0], v0.x, acc0a);
      acc0b = fmaf(a[jc * 4 + 1], v0.y, acc0b);
      acc0a = fmaf(a[jc * 4 + 2], v0.z, acc0a);
      acc0b = fmaf(a[jc * 4 + 3], v0.w, acc0b);
      acc1a = fmaf(a[jc * 4 + 0], v1.x, acc1a);
      acc1b = fmaf(a[jc * 4 + 1], v1.y, acc1b);
      acc1a = fmaf(a[jc * 4 + 2], v1.z, acc1a);
      acc1b = fmaf(a[jc * 4 + 3], v1.w, acc1b);
    }

    float ns0 = tanh_fast(acc0a + acc0b);
    float ns1 = tanh_fast(acc1a + acc1b);
    s_state[nxt][lr0][lane] = ns0;
    s_state[nxt][lr1][lane] = ns1;
    xn1 = xn2;
  }

  // final state is in buffer 0 (T even). Tail projections (still wave-local:
  // tid>>5 covers exactly rows {2w, 2w+1} for wave w).
  const int r_t = tid >> 5;
  const int c_t = tid & 31;

  // observation = W_C @ state + b_C -> s_obs
  {
    const float4* sv = reinterpret_cast<const float4*>(&s_state[0][r_t][0]);
#pragma unroll
    for (int k = 0; k < 4; ++k) {
      const int h = c_t + k * 32;
      float acc = b_C[h];
      const float4* wc = reinterpret_cast<const float4*>(W_C + (size_t)h * S_SZ);
#pragma unroll
      for (int j = 0; j < S_SZ / 4; ++j) {
        float4 w = wc[j];
        float4 s = sv[j];
        acc = fmaf(w.x, s.x, acc);
        acc = fmaf(w.y, s.y, acc);
        acc = fmaf(w.z, s.z, acc);
        acc = fmaf(w.w, s.w, acc);
      }
      s_obs[r_t][h] = acc;
    }
  }

  // h1 = relu(W1 @ obs + b1) -> s_h1
  {
    const float4* ov = reinterpret_cast<const float4*>(&s_obs[r_t][0]);
#pragma unroll
    for (int k = 0; k < 4; ++k) {
      const int h = c_t + k * 32;
      float acc = b1[h];
      const float4* w1 = reinterpret_cast<const float4*>(W1 + (size_t)h * H_SZ);
#pragma unroll
      for (int j = 0; j < H_SZ / 4; ++j) {
        float4 w = w1[j];
        float4 o = ov[j];
        acc = fmaf(w.x, o.x, acc);
        acc = fmaf(w.y, o.y, acc);
        acc = fmaf(w.z, o.z, acc);
        acc = fmaf(w.w, o.w, acc);
      }
      s_h1[r_t][h] = fmaxf(acc, 0.0f);
    }
  }

  // out = W2 @ h1 + b2 (one output element per thread; coalesced store)
  {
    float acc = b2[c_t];
    const float4* w2 = reinterpret_cast<const float4*>(W2 + (size_t)c_t * H_SZ);
    const float4* hv = reinterpret_cast<const float4*>(&s_h1[r_t][0]);
#pragma unroll
    for (int j = 0; j < H_SZ / 4; ++j) {
      float4 w = w2[j];
      float4 h = hv[j];
      acc = fmaf(w.x, h.x, acc);
      acc = fmaf(w.y, h.y, acc);
      acc = fmaf(w.z, h.z, acc);
      acc = fmaf(w.w, h.w, acc);
    }
    out[(size_t)(row_base + r_t) * OUT_SZ + c_t] = acc;
  }
}

extern "C" void kernel_launch(void* const* d_in, const int* in_sizes, int n_in,
                              void* d_out, int out_size, void* d_ws, size_t ws_size,
                              hipStream_t stream) {
  (void)in_sizes; (void)n_in; (void)out_size; (void)d_ws; (void)ws_size;
  const float* x      = (const float*)d_in[0];
  const float* pl     = (const float*)d_in[1];
  const float* W_A    = (const float*)d_in[2];
  const float* W_B    = (const float*)d_in[3];
  const float* W_C    = (const float*)d_in[4];
  const float* b_C    = (const float*)d_in[5];
  const float* W_ctrl = (const float*)d_in[6];
  const float* b_ctrl = (const float*)d_in[7];
  const float* W1     = (const float*)d_in[8];
  const float* b1     = (const float*)d_in[9];
  const float* W2     = (const float*)d_in[10];
  const float* b2     = (const float*)d_in[11];
  float* out = (float*)d_out;

  dim3 grid(B_SZ / ROWS_PER_WG);
  dim3 block(THREADS);
  hipLaunchKernelGGL(ssm_scan_kernel, grid, block, 0, stream,
                     x, pl, W_A, W_B, W_C, b_C, W_ctrl, b_ctrl,
                     W1, b1, W2, b2, out);
}

// Round 3
// 450.859 us; speedup vs baseline: 1.1784x; 1.1446x over previous
//
#include <hip/hip_runtime.h>

#define B_SZ   4096
#define T_SZ   512
#define F_SZ   32
#define S_SZ   64
#define H_SZ   128
#define OUT_SZ 32
#define PH_SZ  6

#define ROWS    16   // batch rows per block (MFMA N)
#define THREADS 256  // 4 waves; wave w owns state i-tile [16w, 16w+16)

typedef __attribute__((ext_vector_type(8))) short bf16x8;  // 8 bf16 (4 VGPRs)
typedef __attribute__((ext_vector_type(4))) float f32x4;

union FragU { uint u[4]; bf16x8 v; };

// pack truncated-bf16 of (a,b) into one u32: low16 = bf16(a), high16 = bf16(b)
__device__ __forceinline__ uint hi_pair(float a, float b) {
  return (__float_as_uint(a) >> 16) | (__float_as_uint(b) & 0xffff0000u);
}
__device__ __forceinline__ float hi_part(float a) {
  return __uint_as_float(__float_as_uint(a) & 0xffff0000u);
}
__device__ __forceinline__ float tanh_fast(float x) {
  // tanh(x) = 1 - 2/(exp(2x)+1); exact at +/-inf
  float e = __expf(2.0f * x);
  return 1.0f - 2.0f * __builtin_amdgcn_rcpf(e + 1.0f);
}

// build hi/lo bf16x8 frags from 8 consecutive floats (two float4)
__device__ __forceinline__ void split_pack(float4 a0, float4 a1, FragU& hi, FragU& lo) {
  hi.u[0] = hi_pair(a0.x, a0.y); hi.u[1] = hi_pair(a0.z, a0.w);
  hi.u[2] = hi_pair(a1.x, a1.y); hi.u[3] = hi_pair(a1.z, a1.w);
  lo.u[0] = hi_pair(a0.x - hi_part(a0.x), a0.y - hi_part(a0.y));
  lo.u[1] = hi_pair(a0.z - hi_part(a0.z), a0.w - hi_part(a0.w));
  lo.u[2] = hi_pair(a1.x - hi_part(a1.x), a1.y - hi_part(a1.y));
  lo.u[3] = hi_pair(a1.z - hi_part(a1.z), a1.w - hi_part(a1.w));
}

#define MFMA(a, b, c) __builtin_amdgcn_mfma_f32_16x16x32_bf16((a), (b), (c), 0, 0, 0)

__global__ __launch_bounds__(THREADS, 2) void ssm_mfma_kernel(
    const float* __restrict__ x, const float* __restrict__ pl,
    const float* __restrict__ W_A, const float* __restrict__ W_B,
    const float* __restrict__ W_C, const float* __restrict__ b_C,
    const float* __restrict__ W_ctrl, const float* __restrict__ b_ctrl,
    const float* __restrict__ W1, const float* __restrict__ b1,
    const float* __restrict__ W2, const float* __restrict__ b2,
    float* __restrict__ out) {
  // state exchange: [buf][plane hi/lo][chunk 0..7][row 0..15][16B]
  // chunk c holds state indices i in [8c, 8c+8) as bf16, k-contiguous per row.
  __shared__ __align__(16) char  s_state[2][2][2048];
  __shared__ __align__(16) float s_final[ROWS][68];
  __shared__ __align__(16) float s_obs[ROWS][132];
  __shared__ __align__(16) float s_h1[ROWS][132];

  const int tid  = threadIdx.x;
  const int lane = tid & 63;
  const int wv   = tid >> 6;       // state i-tile
  const int l15  = lane & 15;      // MFMA row (A) / col (B, C/D)
  const int g    = lane >> 4;      // k-group
  const int rb   = blockIdx.x * ROWS;
  const int rg   = rb + l15;       // this lane's batch row (B-operand col)

  // ---- weight frags (register-resident, hi+lo split) ----
  // A-operand layout: lane holds A[row = l15][k = 8g .. 8g+7]
  FragU Ah0, Al0, Ah1, Al1, Wbh, Wbl;
  {
    const float* wa = W_A + (size_t)(16 * wv + l15) * S_SZ;
    float4 a0 = *(const float4*)(wa + 8 * g);
    float4 a1 = *(const float4*)(wa + 8 * g + 4);
    split_pack(a0, a1, Ah0, Al0);
    float4 a2 = *(const float4*)(wa + 32 + 8 * g);
    float4 a3 = *(const float4*)(wa + 32 + 8 * g + 4);
    split_pack(a2, a3, Ah1, Al1);
    const float* wbp = W_B + (size_t)(16 * wv + l15) * F_SZ + 8 * g;
    float4 b0 = *(const float4*)(wbp);
    float4 b1v = *(const float4*)(wbp + 4);
    split_pack(b0, b1v, Wbh, Wbl);
  }

  // ---- control frag in C/D layout: lane holds (col r = l15, rows i = 16wv+4g+q) ----
  f32x4 ctrl;
#pragma unroll
  for (int q = 0; q < 4; ++q) {
    const int i = 16 * wv + 4 * g + q;
    float c = b_ctrl[i];
#pragma unroll
    for (int p = 0; p < PH_SZ; ++p)
      c = fmaf(W_ctrl[i * PH_SZ + p], pl[(size_t)rg * PH_SZ + p], c);
    ctrl[q] = c;
  }

  // x: lane reads x[rg][t][8g .. 8g+7] (B-operand col=rg, k=f)
  const float4* xp = (const float4*)(x + (size_t)rg * T_SZ * F_SZ) + 2 * g;

  // LDS offsets
  const int wr_off = (2 * wv + (g >> 1)) * 256 + l15 * 16 + (g & 1) * 8;
  const int rd0 = g * 256 + l15 * 16;        // k-tile 0: chunks 0..3
  const int rd1 = (g + 4) * 256 + l15 * 16;  // k-tile 1: chunks 4..7

  bf16x8 sh0 = {0,0,0,0,0,0,0,0}, sh1 = sh0, sl0 = sh0, sl1 = sh0;  // state_0 = 0
  float4 xa = xp[0], xb = xp[1];

#pragma unroll 2
  for (int t = 0; t < T_SZ; ++t) {
    const int nb = (t + 1) & 1;

    // x frags (hi/lo split, truncation)
    FragU xh, xl;
    split_pack(xa, xb, xh, xl);

    // prefetch next step's x (wraps harmlessly at t=511)
    const int tn = (t + 1) & (T_SZ - 1);
    float4 na  = xp[(size_t)tn * 8];
    float4 nbv = xp[(size_t)tn * 8 + 1];

    // D = A_hi s_hi + A_hi s_lo + A_lo s_hi + Wb_hi x_hi + Wb_hi x_lo + Wb_lo x_hi + ctrl
    // three independent accumulator chains (3-deep each)
    f32x4 accA = ctrl;
    f32x4 accB = {0.f, 0.f, 0.f, 0.f};
    f32x4 accC = {0.f, 0.f, 0.f, 0.f};
    accA = MFMA(Ah0.v, sh0, accA);
    accB = MFMA(Ah0.v, sl0, accB);
    accC = MFMA(Al0.v, sh0, accC);
    accA = MFMA(Ah1.v, sh1, accA);
    accB = MFMA(Ah1.v, sl1, accB);
    accC = MFMA(Al1.v, sh1, accC);
    accA = MFMA(Wbh.v, xh.v, accA);
    accB = MFMA(Wbh.v, xl.v, accB);
    accC = MFMA(Wbl.v, xh.v, accC);

    const float s0 = tanh_fast(accA[0] + accB[0] + accC[0]);
    const float s1 = tanh_fast(accA[1] + accB[1] + accC[1]);
    const float s2 = tanh_fast(accA[2] + accB[2] + accC[2]);
    const float s3 = tanh_fast(accA[3] + accB[3] + accC[3]);

    // split + write new state (D layout: col r=l15, rows i=16wv+4g+q)
    const uint hp0 = hi_pair(s0, s1), hp1 = hi_pair(s2, s3);
    const uint lp0 = hi_pair(s0 - hi_part(s0), s1 - hi_part(s1));
    const uint lp1 = hi_pair(s2 - hi_part(s2), s3 - hi_part(s3));
    *(uint2*)(&s_state[nb][0][wr_off]) = make_uint2(hp0, hp1);
    *(uint2*)(&s_state[nb][1][wr_off]) = make_uint2(lp0, lp1);

    if (t == T_SZ - 1) {
      *(float4*)(&s_final[l15][16 * wv + 4 * g]) = make_float4(s0, s1, s2, s3);
    }

    __syncthreads();

    // read B-frags for next step: lane (col r=l15, k = 8g..8g+7 / 32+8g..+7)
    sh0 = *(const bf16x8*)(&s_state[nb][0][rd0]);
    sh1 = *(const bf16x8*)(&s_state[nb][0][rd1]);
    sl0 = *(const bf16x8*)(&s_state[nb][1][rd0]);
    sl1 = *(const bf16x8*)(&s_state[nb][1][rd1]);
    xa = na; xb = nbv;
  }

  // ---- tail projections (fp32 VALU, once per block) ----
  const int rt = tid >> 4;   // 0..15 local row
  const int ct = tid & 15;   // 0..15

  // observation = W_C @ state + b_C
#pragma unroll
  for (int k = 0; k < 8; ++k) {
    const int h = ct + 16 * k;
    float acc = b_C[h];
    const float4* wc = (const float4*)(W_C + (size_t)h * S_SZ);
    const float4* sv = (const float4*)(&s_final[rt][0]);
#pragma unroll
    for (int j = 0; j < S_SZ / 4; ++j) {
      float4 w = wc[j]; float4 s = sv[j];
      acc = fmaf(w.x, s.x, acc); acc = fmaf(w.y, s.y, acc);
      acc = fmaf(w.z, s.z, acc); acc = fmaf(w.w, s.w, acc);
    }
    s_obs[rt][h] = acc;
  }
  __syncthreads();

  // h1 = relu(W1 @ obs + b1)
#pragma unroll
  for (int k = 0; k < 8; ++k) {
    const int h = ct + 16 * k;
    float acc = b1[h];
    const float4* w1 = (const float4*)(W1 + (size_t)h * H_SZ);
    const float4* ov = (const float4*)(&s_obs[rt][0]);
#pragma unroll
    for (int j = 0; j < H_SZ / 4; ++j) {
      float4 w = w1[j]; float4 o = ov[j];
      acc = fmaf(w.x, o.x, acc); acc = fmaf(w.y, o.y, acc);
      acc = fmaf(w.z, o.z, acc); acc = fmaf(w.w, o.w, acc);
    }
    s_h1[rt][h] = fmaxf(acc, 0.0f);
  }
  __syncthreads();

  // out = W2 @ h1 + b2
#pragma unroll
  for (int it = 0; it < 2; ++it) {
    const int idx = tid + 256 * it;
    const int r = idx >> 5;
    const int c = idx & 31;
    float acc = b2[c];
    const float4* w2 = (const float4*)(W2 + (size_t)c * H_SZ);
    const float4* hv = (const float4*)(&s_h1[r][0]);
#pragma unroll
    for (int j = 0; j < H_SZ / 4; ++j) {
      float4 w = w2[j]; float4 h = hv[j];
      acc = fmaf(w.x, h.x, acc); acc = fmaf(w.y, h.y, acc);
      acc = fmaf(w.z, h.z, acc); acc = fmaf(w.w, h.w, acc);
    }
    out[(size_t)(rb + r) * OUT_SZ + c] = acc;
  }
}

extern "C" void kernel_launch(void* const* d_in, const int* in_sizes, int n_in,
                              void* d_out, int out_size, void* d_ws, size_t ws_size,
                              hipStream_t stream) {
  (void)in_sizes; (void)n_in; (void)out_size; (void)d_ws; (void)ws_size;
  const float* x      = (const float*)d_in[0];
  const float* pl     = (const float*)d_in[1];
  const float* W_A    = (const float*)d_in[2];
  const float* W_B    = (const float*)d_in[3];
  const float* W_C    = (const float*)d_in[4];
  const float* b_C    = (const float*)d_in[5];
  const float* W_ctrl = (const float*)d_in[6];
  const float* b_ctrl = (const float*)d_in[7];
  const float* W1     = (const float*)d_in[8];
  const float* b1     = (const float*)d_in[9];
  const float* W2     = (const float*)d_in[10];
  const float* b2     = (const float*)d_in[11];
  float* out = (float*)d_out;

  dim3 grid(B_SZ / ROWS);
  dim3 block(THREADS);
  hipLaunchKernelGGL(ssm_mfma_kernel, grid, block, 0, stream,
                     x, pl, W_A, W_B, W_C, b_C, W_ctrl, b_ctrl,
                     W1, b1, W2, b2, out);
}

// Round 4
// 334.978 us; speedup vs baseline: 1.5860x; 1.3459x over previous
//
#include <hip/hip_runtime.h>

#define B_SZ   4096
#define T_SZ   512
#define F_SZ   32
#define S_SZ   64
#define H_SZ   128
#define OUT_SZ 32
#define PH_SZ  6

#define ROWS    16   // batch rows per block (MFMA N)
#define THREADS 256  // 4 waves; wave w owns state i-tile [16w, 16w+16)

typedef __attribute__((ext_vector_type(8))) short bf16x8;  // 8 bf16 (4 VGPRs)
typedef __attribute__((ext_vector_type(4))) float f32x4;

union FragU { uint u[4]; bf16x8 v; };

// pack truncated-bf16 of (a,b) into one u32: low16 = bf16(a), high16 = bf16(b)
__device__ __forceinline__ uint hi_pair(float a, float b) {
  return (__float_as_uint(a) >> 16) | (__float_as_uint(b) & 0xffff0000u);
}
__device__ __forceinline__ float hi_part(float a) {
  return __uint_as_float(__float_as_uint(a) & 0xffff0000u);
}
__device__ __forceinline__ float tanh_fast(float x) {
  float e = __expf(2.0f * x);
  return 1.0f - 2.0f * __builtin_amdgcn_rcpf(e + 1.0f);
}

__device__ __forceinline__ void split_pack(float4 a0, float4 a1, FragU& hi, FragU& lo) {
  hi.u[0] = hi_pair(a0.x, a0.y); hi.u[1] = hi_pair(a0.z, a0.w);
  hi.u[2] = hi_pair(a1.x, a1.y); hi.u[3] = hi_pair(a1.z, a1.w);
  lo.u[0] = hi_pair(a0.x - hi_part(a0.x), a0.y - hi_part(a0.y));
  lo.u[1] = hi_pair(a0.z - hi_part(a0.z), a0.w - hi_part(a0.w));
  lo.u[2] = hi_pair(a1.x - hi_part(a1.x), a1.y - hi_part(a1.y));
  lo.u[3] = hi_pair(a1.z - hi_part(a1.z), a1.w - hi_part(a1.w));
}

#define MFMA(a, b, c) __builtin_amdgcn_mfma_f32_16x16x32_bf16((a), (b), (c), 0, 0, 0)

// barrier WITHOUT vmcnt drain: LDS writes visible, global prefetch stays in flight
#define WAVE_BARRIER() do { \
    asm volatile("s_waitcnt lgkmcnt(0)" ::: "memory"); \
    __builtin_amdgcn_s_barrier(); \
    asm volatile("" ::: "memory"); \
  } while (0)

__global__ __launch_bounds__(THREADS, 2) void ssm_mfma_kernel(
    const float* __restrict__ x, const float* __restrict__ pl,
    const float* __restrict__ W_A, const float* __restrict__ W_B,
    const float* __restrict__ W_C, const float* __restrict__ b_C,
    const float* __restrict__ W_ctrl, const float* __restrict__ b_ctrl,
    const float* __restrict__ W1, const float* __restrict__ b1,
    const float* __restrict__ W2, const float* __restrict__ b2,
    float* __restrict__ out) {
  // state exchange: [buf][plane hi/lo][chunk 0..7][row 0..15][16B], XOR-swizzled
  __shared__ __align__(16) char  s_state[2][2][2048];
  __shared__ __align__(16) float s_final[ROWS][68];
  __shared__ __align__(16) float s_obs[ROWS][132];
  __shared__ __align__(16) float s_h1[ROWS][132];

  const int tid  = threadIdx.x;
  const int lane = tid & 63;
  const int wv   = tid >> 6;
  const int l15  = lane & 15;
  const int g    = lane >> 4;
  const int rb   = blockIdx.x * ROWS;
  const int rg   = rb + l15;

  // ---- weight frags (register-resident, hi+lo split) ----
  FragU Ah0, Al0, Ah1, Al1, Wbh, Wbl;
  {
    const float* wa = W_A + (size_t)(16 * wv + l15) * S_SZ;
    float4 a0 = *(const float4*)(wa + 8 * g);
    float4 a1 = *(const float4*)(wa + 8 * g + 4);
    split_pack(a0, a1, Ah0, Al0);
    float4 a2 = *(const float4*)(wa + 32 + 8 * g);
    float4 a3 = *(const float4*)(wa + 32 + 8 * g + 4);
    split_pack(a2, a3, Ah1, Al1);
    const float* wbp = W_B + (size_t)(16 * wv + l15) * F_SZ + 8 * g;
    float4 b0 = *(const float4*)(wbp);
    float4 b1v = *(const float4*)(wbp + 4);
    split_pack(b0, b1v, Wbh, Wbl);
  }

  // ---- control frag in C/D layout ----
  f32x4 ctrl;
#pragma unroll
  for (int q = 0; q < 4; ++q) {
    const int i = 16 * wv + 4 * g + q;
    float c = b_ctrl[i];
#pragma unroll
    for (int p = 0; p < PH_SZ; ++p)
      c = fmaf(W_ctrl[i * PH_SZ + p], pl[(size_t)rg * PH_SZ + p], c);
    ctrl[q] = c;
  }

  // x: lane reads x[rg][t][8g .. 8g+7]
  const float4* xp = (const float4*)(x + (size_t)rg * T_SZ * F_SZ) + 2 * g;

  // LDS offsets (XOR-swizzled: row bits ^ chunk low bits -> 8-way becomes 2-way)
  const int cw     = 2 * wv + (g >> 1);
  const int wr_off = cw * 256 + ((l15 * 16) ^ ((cw & 3) << 4)) + (g & 1) * 8;
  const int rsw    = (l15 * 16) ^ ((g & 3) << 4);
  const int rd0    = g * 256 + rsw;
  const int rd1    = (g + 4) * 256 + rsw;

  bf16x8 sh0 = {0,0,0,0,0,0,0,0}, sh1 = sh0, sl0 = sh0, sl1 = sh0;
  // distance-2 prefetch: even steps use xA, odd steps use xB
  float4 xA0 = xp[0], xA1 = xp[1];   // t = 0
  float4 xB0 = xp[8], xB1 = xp[9];   // t = 1

#define STEP(T_, X0_, X1_, NB_, LAST_)                                          \
  {                                                                             \
    FragU xh, xl;                                                               \
    split_pack(X0_, X1_, xh, xl);        /* hides prev ds_read latency */       \
    {                                    /* issue prefetch for T_+2 */          \
      const int tn = ((T_) + 2) & (T_SZ - 1);                                   \
      X0_ = xp[(size_t)tn * 8];                                                 \
      X1_ = xp[(size_t)tn * 8 + 1];                                             \
    }                                                                           \
    f32x4 accA = ctrl;                                                          \
    f32x4 accB = {0.f, 0.f, 0.f, 0.f};                                          \
    f32x4 accC = {0.f, 0.f, 0.f, 0.f};                                          \
    accA = MFMA(Ah0.v, sh0, accA);                                              \
    accB = MFMA(Ah0.v, sl0, accB);                                              \
    accC = MFMA(Al0.v, sh0, accC);                                              \
    accA = MFMA(Ah1.v, sh1, accA);                                              \
    accB = MFMA(Ah1.v, sl1, accB);                                              \
    accC = MFMA(Al1.v, sh1, accC);                                              \
    accA = MFMA(Wbh.v, xh.v, accA);                                             \
    accB = MFMA(Wbh.v, xl.v, accB);                                             \
    accC = MFMA(Wbl.v, xh.v, accC);                                             \
    const float s0 = tanh_fast(accA[0] + accB[0] + accC[0]);                    \
    const float s1 = tanh_fast(accA[1] + accB[1] + accC[1]);                    \
    const float s2 = tanh_fast(accA[2] + accB[2] + accC[2]);                    \
    const float s3 = tanh_fast(accA[3] + accB[3] + accC[3]);                    \
    const uint hp0 = hi_pair(s0, s1), hp1 = hi_pair(s2, s3);                    \
    const uint lp0 = hi_pair(s0 - hi_part(s0), s1 - hi_part(s1));               \
    const uint lp1 = hi_pair(s2 - hi_part(s2), s3 - hi_part(s3));               \
    *(uint2*)(&s_state[NB_][0][wr_off]) = make_uint2(hp0, hp1);                 \
    *(uint2*)(&s_state[NB_][1][wr_off]) = make_uint2(lp0, lp1);                 \
    if (LAST_)                                                                  \
      *(float4*)(&s_final[l15][16 * wv + 4 * g]) = make_float4(s0, s1, s2, s3); \
    WAVE_BARRIER();                                                             \
    sh0 = *(const bf16x8*)(&s_state[NB_][0][rd0]);                              \
    sh1 = *(const bf16x8*)(&s_state[NB_][0][rd1]);                              \
    sl0 = *(const bf16x8*)(&s_state[NB_][1][rd0]);                              \
    sl1 = *(const bf16x8*)(&s_state[NB_][1][rd1]);                              \
  }

  for (int t = 0; t < T_SZ; t += 2) {
    STEP(t,     xA0, xA1, 1, false)              // even step -> buffer 1
    STEP(t + 1, xB0, xB1, 0, (t == T_SZ - 2))    // odd step  -> buffer 0
  }
#undef STEP

  // ---- tail projections (once per block; plain __syncthreads OK here) ----
  const int rt = tid >> 4;
  const int ct = tid & 15;

#pragma unroll
  for (int k = 0; k < 8; ++k) {
    const int h = ct + 16 * k;
    float acc = b_C[h];
    const float4* wc = (const float4*)(W_C + (size_t)h * S_SZ);
    const float4* sv = (const float4*)(&s_final[rt][0]);
#pragma unroll
    for (int j = 0; j < S_SZ / 4; ++j) {
      float4 w = wc[j]; float4 s = sv[j];
      acc = fmaf(w.x, s.x, acc); acc = fmaf(w.y, s.y, acc);
      acc = fmaf(w.z, s.z, acc); acc = fmaf(w.w, s.w, acc);
    }
    s_obs[rt][h] = acc;
  }
  __syncthreads();

#pragma unroll
  for (int k = 0; k < 8; ++k) {
    const int h = ct + 16 * k;
    float acc = b1[h];
    const float4* w1 = (const float4*)(W1 + (size_t)h * H_SZ);
    const float4* ov = (const float4*)(&s_obs[rt][0]);
#pragma unroll
    for (int j = 0; j < H_SZ / 4; ++j) {
      float4 w = w1[j]; float4 o = ov[j];
      acc = fmaf(w.x, o.x, acc); acc = fmaf(w.y, o.y, acc);
      acc = fmaf(w.z, o.z, acc); acc = fmaf(w.w, o.w, acc);
    }
    s_h1[rt][h] = fmaxf(acc, 0.0f);
  }
  __syncthreads();

#pragma unroll
  for (int it = 0; it < 2; ++it) {
    const int idx = tid + 256 * it;
    const int r = idx >> 5;
    const int c = idx & 31;
    float acc = b2[c];
    const float4* w2 = (const float4*)(W2 + (size_t)c * H_SZ);
    const float4* hv = (const float4*)(&s_h1[r][0]);
#pragma unroll
    for (int j = 0; j < H_SZ / 4; ++j) {
      float4 w = w2[j]; float4 h = hv[j];
      acc = fmaf(w.x, h.x, acc); acc = fmaf(w.y, h.y, acc);
      acc = fmaf(w.z, h.z, acc); acc = fmaf(w.w, h.w, acc);
    }
    out[(size_t)(rb + r) * OUT_SZ + c] = acc;
  }
}

extern "C" void kernel_launch(void* const* d_in, const int* in_sizes, int n_in,
                              void* d_out, int out_size, void* d_ws, size_t ws_size,
                              hipStream_t stream) {
  (void)in_sizes; (void)n_in; (void)out_size; (void)d_ws; (void)ws_size;
  const float* x      = (const float*)d_in[0];
  const float* pl     = (const float*)d_in[1];
  const float* W_A    = (const float*)d_in[2];
  const float* W_B    = (const float*)d_in[3];
  const float* W_C    = (const float*)d_in[4];
  const float* b_C    = (const float*)d_in[5];
  const float* W_ctrl = (const float*)d_in[6];
  const float* b_ctrl = (const float*)d_in[7];
  const float* W1     = (const float*)d_in[8];
  const float* b1     = (const float*)d_in[9];
  const float* W2     = (const float*)d_in[10];
  const float* b2     = (const float*)d_in[11];
  float* out = (float*)d_out;

  dim3 grid(B_SZ / ROWS);
  dim3 block(THREADS);
  hipLaunchKernelGGL(ssm_mfma_kernel, grid, block, 0, stream,
                     x, pl, W_A, W_B, W_C, b_C, W_ctrl, b_ctrl,
                     W1, b1, W2, b2, out);
}